// Round 7
// baseline (428.913 us; speedup 1.0000x reference)
//
#include <hip/hip_runtime.h>

// Frobenius_71975061946522 — R7: persistent-in-VGPR, barrier-FREE tagged
// dataflow. X (4096x4096 fp32, 64 MB) lives in the unified VGPR/AGPR file
// for all 20 iterations: 256 blocks x 1024 threads (1 block/CU); thread t of
// block b holds X[16b+r][4t..4t+3], r=0..15.
//
// R6 lesson: 2 grid barriers/iter cost ~9 of 11.8 us/iter (VALU-busy only
// ~2.4). Barriers are overkill: the true deps are point-to-point. All
// cross-block floats are exchanged as (fp32 value | u32 iter-tag) packed in
// ONE relaxed agent-scope b64 atomic store; consumers spin on exact tag.
//   phase1: block b stores colpart[b][j] tagged iter (single buffer —
//           WAR-safe: thread t overwrites cols 4t..4t+3 only after its
//           phase3 poll of col_out[4t..4t+3], whose producer block t/4
//           published only after __syncthreads-ordered reads of ALL its
//           colpart inputs, including this thread's).
//   phase2: block b polls the 256 partials for its 16 columns, folds in
//           LDS, publishes col_out[parity][16b..16b+16) tagged iter.
//           (parity-2: overwrite at k+2 is gated through every block's
//           colpart-(k+2) stores, which follow their phase3-(k+1).)
//   phase3: thread t polls its 4 col_out entries (one producer block),
//           redundant grand total per block, in-register update.
// Zero fences, zero barriers, zero atomic-RMW anywhere.

#define NN    4096
#define NV4   1024
#define RPB   16
#define NBLK  256
#define ITERS 20
#define INV_N (1.0f / 4096.0f)

typedef unsigned long long u64;

__device__ __forceinline__ float wave_reduce_sum(float v) {
    #pragma unroll
    for (int m = 1; m < 64; m <<= 1) v += __shfl_xor(v, m, 64);
    return v;
}

__device__ __forceinline__ void st_tagged(u64* p, float v, unsigned tag) {
    u64 u = (u64)__float_as_uint(v) | ((u64)tag << 32);
    __hip_atomic_store(p, u, __ATOMIC_RELAXED, __HIP_MEMORY_SCOPE_AGENT);
}
__device__ __forceinline__ float poll_tagged(const u64* p, unsigned tag) {
    u64 u;
    do {
        u = __hip_atomic_load(p, __ATOMIC_RELAXED, __HIP_MEMORY_SCOPE_AGENT);
    } while ((unsigned)(u >> 32) != tag);
    return __uint_as_float((unsigned)u);
}

__global__ __launch_bounds__(1024, 4)
void persist6(const float* __restrict__ X0, float* __restrict__ Xout,
              u64* __restrict__ colpart,    // [NBLK][NN] tagged
              u64* __restrict__ col_out)    // [2][NN] tagged (parity)
{
    const int t    = threadIdx.x;
    const int wave = t >> 6;
    const int lane = t & 63;
    const int b    = blockIdx.x;
    const int row0 = b * RPB;

    __shared__ float part[1024 * 17];   // row-partial transpose (pad 17)
    __shared__ float csum[64 * 17];     // phase2 fold (pad 17)
    __shared__ float rowsum[RPB];
    __shared__ float sred[16];

    // Load this thread's 16 float4 of X into registers.
    float4 x[RPB];
    const float4* x0 = (const float4*)X0;
    #pragma unroll
    for (int r = 0; r < RPB; ++r)
        x[r] = x0[(size_t)(row0 + r) * NV4 + t];

    for (unsigned iter = 0; iter < ITERS; ++iter) {
        // ---- phase 1: column partials -> tagged stores (ASAP); row sums -> LDS
        float4 cacc = make_float4(0.f, 0.f, 0.f, 0.f);
        #pragma unroll
        for (int r = 0; r < RPB; ++r) {
            cacc.x += x[r].x; cacc.y += x[r].y;
            cacc.z += x[r].z; cacc.w += x[r].w;
        }
        {
            u64* cp = colpart + (size_t)b * NN + 4 * t;
            st_tagged(cp + 0, cacc.x, iter);
            st_tagged(cp + 1, cacc.y, iter);
            st_tagged(cp + 2, cacc.z, iter);
            st_tagged(cp + 3, cacc.w, iter);
        }
        #pragma unroll
        for (int r = 0; r < RPB; ++r)
            part[t * 17 + r] = (x[r].x + x[r].y) + (x[r].z + x[r].w);
        __syncthreads();   // part[] ready; also orders prior-iter rowsum reads
        {   // wave w reduces row w (stride-17 -> <=2-way alias, free)
            float v = 0.f;
            #pragma unroll
            for (int k = 0; k < 16; ++k)
                v += part[(lane + 64 * k) * 17 + wave];
            v = wave_reduce_sum(v);
            if (lane == 0) rowsum[wave] = v;
        }

        // ---- phase 2: block b reduces columns [16b, 16b+16) via tag-polls
        {
            const int jl = t & 15;                 // column within the 16
            const int c  = t >> 4;                 // chunk 0..63 (4 rows each)
            const u64* q = colpart + (size_t)(4 * c) * NN + (b << 4) + jl;
            float p = poll_tagged(q,            iter)
                    + poll_tagged(q +     NN,   iter)
                    + poll_tagged(q + 2 * NN,   iter)
                    + poll_tagged(q + 3 * NN,   iter);
            csum[c * 17 + jl] = p;
            __syncthreads();   // ALL colpart reads done before any publish
            // wave w folds column w: lane l reads csum[l][w] (17-pad: free)
            float v = csum[lane * 17 + wave];
            v = wave_reduce_sum(v);
            if (lane == 0)
                st_tagged(col_out + (size_t)(iter & 1) * NN + (b << 4) + wave,
                          v, iter);
        }

        // ---- phase 3: poll own 4 col sums, redundant total, update X
        const u64* co = col_out + (size_t)(iter & 1) * NN + 4 * t;
        float4 cv;
        cv.x = poll_tagged(co + 0, iter);
        cv.y = poll_tagged(co + 1, iter);
        cv.z = poll_tagged(co + 2, iter);
        cv.w = poll_tagged(co + 3, iter);
        {   // redundant grand total (identical fold order in every block)
            float cs = (cv.x + cv.y) + (cv.z + cv.w);
            cs = wave_reduce_sum(cs);
            if (lane == 0) sred[wave] = cs;
        }
        __syncthreads();
        float s = 0.f;
        #pragma unroll
        for (int w = 0; w < 16; ++w) s += sred[w];

        const float c0 = INV_N + s * (INV_N * INV_N);
        float4 csub;
        csub.x = cv.x * INV_N; csub.y = cv.y * INV_N;
        csub.z = cv.z * INV_N; csub.w = cv.w * INV_N;
        #pragma unroll
        for (int r = 0; r < RPB; ++r) {
            const float a = c0 - rowsum[r] * INV_N;
            x[r].x = fmaxf(x[r].x + a - csub.x, 0.f);
            x[r].y = fmaxf(x[r].y + a - csub.y, 0.f);
            x[r].z = fmaxf(x[r].z + a - csub.z, 0.f);
            x[r].w = fmaxf(x[r].w + a - csub.w, 0.f);
        }
        // next iteration's __syncthreads protects rowsum/sred/part reuse
    }

    // Final store.
    float4* xo = (float4*)Xout;
    #pragma unroll
    for (int r = 0; r < RPB; ++r)
        xo[(size_t)(row0 + r) * NV4 + t] = x[r];
}

extern "C" void kernel_launch(void* const* d_in, const int* in_sizes, int n_in,
                              void* d_out, int out_size, void* d_ws, size_t ws_size,
                              hipStream_t stream)
{
    const float* X0 = (const float*)d_in[0];
    float* X = (float*)d_out;

    // ws layout (u64): colpart[256*4096] (8 MB) | col_out[2*4096] (64 KB)
    u64* colpart = (u64*)d_ws;
    u64* col_out = colpart + (size_t)NBLK * NN;

    // Poison tags so no entry matches tag 0..19 at start (0xAAAAAAAA tag).
    hipMemsetAsync(d_ws, 0xAA,
                   ((size_t)NBLK * NN + 2 * NN) * sizeof(u64), stream);

    // Regular launch: 1 block/CU (74 KB LDS, 16 waves), grid == CU count ->
    // co-residency structural; no CG API used.
    persist6<<<dim3(NBLK), dim3(1024), 0, stream>>>(X0, X, colpart, col_out);
}

// Round 9
// 268.051 us; speedup vs baseline: 1.6001x; 1.6001x over previous
//
#include <hip/hip_runtime.h>

// Frobenius_71975061946522 — R9: persistent-in-VGPR, barrier-free flag-gated
// dataflow; ALL cross-block data via b64 relaxed agent-scope atomics.
//
// X (4096x4096 fp32, 64 MB) lives in the unified VGPR/AGPR file for all 20
// iterations: 256 blocks x 1024 threads (1 block/CU); thread t of block b
// holds X[16b+r][4t..4t+3], r=0..15.
//
// R8 lesson: plain global_store_dwordx4 with sc0 sc1 does NOT reach the
// coherence point the way atomic stores do (flag visible, data stale ->
// absmax 1.1). Cross-XCD data must move via atomic ops: b64 relaxed agent
// atomics (2 packed floats), the primitive proven in R5/R6/R7.
//
// Dataflow (zero barriers, zero fences, zero RMW):
//   phase1: block b publishes colpart[b][4096] (2 b64 atomic stores/thread),
//           drains own vmem, __syncthreads, then t0 sets flag1[b]=iter+1.
//           Row sums fold block-locally meanwhile (LDS transpose).
//   phase2: wave w waits flag1 of blocks [16w,16w+16) (16 polling lanes);
//           thread t loads 4 floats of colpart[16w+(l>>2)] (2 b64 loads),
//           butterfly over lane bits 2..5, wql fold, wave 0 publishes
//           col_out[16b..16b+16), t0 sets flag2[b]=iter+1.
//   phase3: wave w waits flag2 of blocks [16w,16w+16); thread t loads its 4
//           col sums, redundant per-block grand total, in-register update.
//
// WAR safety (single-buffered colpart/col_out, monotone flags):
//  - colpart[b][4t..4t+3] rewritten at k+1 only after thread t passed
//    phase3-k wait on flag2[t>>2], set by block t>>2 only after ALL its
//    phase2-k colpart reads (sync (A)-ordered).
//  - col_out[16b..) rewritten at k+1 only after block b saw ALL flag1=k+2,
//    each set after that block's phase3-k col_out reads (program order).

#define NN    4096
#define NV4   1024
#define RPB   16
#define NBLK  256
#define ITERS 20
#define INV_N (1.0f / 4096.0f)
#define PSTR  21            // part[] stride: odd (conflict-free) and big
                            // enough to push LDS > 80 KB -> 1 block/CU

typedef unsigned long long u64;
typedef float f32x4 __attribute__((ext_vector_type(4)));

__device__ __forceinline__ float wave_reduce_sum(float v) {
    #pragma unroll
    for (int m = 1; m < 64; m <<= 1) v += __shfl_xor(v, m, 64);
    return v;
}

__device__ __forceinline__ void st_atomic_f32x2(float* p, float a, float b) {
    u64 u = (u64)__float_as_uint(a) | ((u64)__float_as_uint(b) << 32);
    __hip_atomic_store((u64*)p, u, __ATOMIC_RELAXED, __HIP_MEMORY_SCOPE_AGENT);
}
__device__ __forceinline__ float2 ld_atomic_f32x2(const float* p) {
    u64 u = __hip_atomic_load((const u64*)p, __ATOMIC_RELAXED,
                              __HIP_MEMORY_SCOPE_AGENT);
    return make_float2(__uint_as_float((unsigned)u),
                       __uint_as_float((unsigned)(u >> 32)));
}

// Lanes 0..15 of each wave poll flags[16*wave + lane] until >= tgt.
// Covers exactly the producer blocks this wave consumes in phases 2 and 3.
__device__ __forceinline__ void wait_flags(const u64* flags, int wave, int lane, u64 tgt) {
    if (lane < 16) {
        const u64* f = flags + (size_t)(wave * 16 + lane) * 8;   // 64 B apart
        while (__hip_atomic_load(f, __ATOMIC_RELAXED, __HIP_MEMORY_SCOPE_AGENT) < tgt)
            __builtin_amdgcn_s_sleep(1);
    }
    asm volatile("" ::: "memory");   // no hoisting across the poll
}

__global__ __launch_bounds__(1024, 4)
void persist8(const float* __restrict__ X0, float* __restrict__ Xout,
              float* __restrict__ colpart,   // [NBLK][NN]
              float* __restrict__ col_out,   // [NN]
              u64* __restrict__ flag1,       // [NBLK] stride 8 (64 B)
              u64* __restrict__ flag2)       // [NBLK] stride 8
{
    const int t    = threadIdx.x;
    const int wave = t >> 6;
    const int lane = t & 63;
    const int b    = blockIdx.x;
    const int row0 = b * RPB;

    __shared__ float part[1024 * PSTR];   // row-partial transpose (~84 KB)
    __shared__ f32x4 wql[64];             // per-wave column-partial quads
    __shared__ float rowsum[RPB];
    __shared__ float sred[16];

    // Load this thread's 16 float4 of X into registers.
    f32x4 x[RPB];
    const f32x4* x0 = (const f32x4*)X0;
    #pragma unroll
    for (int r = 0; r < RPB; ++r)
        x[r] = x0[(size_t)(row0 + r) * NV4 + t];

    for (unsigned iter = 0; iter < ITERS; ++iter) {
        const u64 tgt = (u64)iter + 1;

        // ---- phase 1: column partials -> 2 b64 atomic stores (ASAP)
        f32x4 cacc = x[0];
        #pragma unroll
        for (int r = 1; r < RPB; ++r) cacc += x[r];
        {
            float* cp = colpart + (size_t)b * NN + 4 * t;
            st_atomic_f32x2(cp,     cacc.x, cacc.y);
            st_atomic_f32x2(cp + 2, cacc.z, cacc.w);
        }
        #pragma unroll
        for (int r = 0; r < RPB; ++r)
            part[t * PSTR + r] = (x[r].x + x[r].y) + (x[r].z + x[r].w);
        asm volatile("s_waitcnt vmcnt(0)" ::: "memory");   // own stores done
        __syncthreads();                                    // all threads'
        if (t == 0)
            __hip_atomic_store(flag1 + (size_t)b * 8, tgt,
                               __ATOMIC_RELAXED, __HIP_MEMORY_SCOPE_AGENT);
        {   // wave w folds band-row w (odd stride -> <=2-way alias, free)
            float v = 0.f;
            #pragma unroll
            for (int k = 0; k < 16; ++k)
                v += part[(lane + 64 * k) * PSTR + wave];
            v = wave_reduce_sum(v);
            if (lane == 0) rowsum[wave] = v;
        }

        // ---- phase 2: block b reduces columns [16b, 16b+16)
        wait_flags(flag1, wave, lane, tgt);
        {
            const int blk = 16 * wave + (lane >> 2);   // source block
            const int q   = lane & 3;                  // quad within 16 cols
            const float* cp = colpart + (size_t)blk * NN + (b << 4) + 4 * q;
            float2 a01 = ld_atomic_f32x2(cp);
            float2 a23 = ld_atomic_f32x2(cp + 2);
            f32x4 v; v.x = a01.x; v.y = a01.y; v.z = a23.x; v.w = a23.y;
            #pragma unroll
            for (int m = 4; m <= 32; m <<= 1) {        // fold 16 blocks
                v.x += __shfl_xor(v.x, m, 64);
                v.y += __shfl_xor(v.y, m, 64);
                v.z += __shfl_xor(v.z, m, 64);
                v.w += __shfl_xor(v.w, m, 64);
            }
            if (lane < 4) wql[wave * 4 + lane] = v;    // lane == q here
        }
        __syncthreads();                               // (A) wql complete
        if (wave == 0) {
            f32x4 u = wql[lane];                       // lane = w2*4 + q
            #pragma unroll
            for (int m = 4; m <= 32; m <<= 1) {        // fold 16 waves
                u.x += __shfl_xor(u.x, m, 64);
                u.y += __shfl_xor(u.y, m, 64);
                u.z += __shfl_xor(u.z, m, 64);
                u.w += __shfl_xor(u.w, m, 64);
            }
            if (lane < 4) {
                float* co = col_out + (b << 4) + 4 * lane;
                st_atomic_f32x2(co,     u.x, u.y);
                st_atomic_f32x2(co + 2, u.z, u.w);
            }
            asm volatile("s_waitcnt vmcnt(0)" ::: "memory");
        }
        __syncthreads();                               // (B) col_out drained
        if (t == 0)
            __hip_atomic_store(flag2 + (size_t)b * 8, tgt,
                               __ATOMIC_RELAXED, __HIP_MEMORY_SCOPE_AGENT);

        // ---- phase 3: own 4 column sums (producer block = t>>2)
        wait_flags(flag2, wave, lane, tgt);
        float2 ab = ld_atomic_f32x2(col_out + 4 * t);
        float2 cd = ld_atomic_f32x2(col_out + 4 * t + 2);
        f32x4 cv; cv.x = ab.x; cv.y = ab.y; cv.z = cd.x; cv.w = cd.y;
        {   // redundant grand total (identical fold order in every block)
            float cs = (cv.x + cv.y) + (cv.z + cv.w);
            cs = wave_reduce_sum(cs);
            if (lane == 0) sred[wave] = cs;
        }
        __syncthreads();
        float s = 0.f;
        #pragma unroll
        for (int w = 0; w < 16; ++w) s += sred[w];

        const float c0 = INV_N + s * (INV_N * INV_N);
        const f32x4 csub = cv * INV_N;
        #pragma unroll
        for (int r = 0; r < RPB; ++r) {
            const float a = c0 - rowsum[r] * INV_N;
            x[r].x = fmaxf(x[r].x + a - csub.x, 0.f);
            x[r].y = fmaxf(x[r].y + a - csub.y, 0.f);
            x[r].z = fmaxf(x[r].z + a - csub.z, 0.f);
            x[r].w = fmaxf(x[r].w + a - csub.w, 0.f);
        }
        // next iteration's phase-1 __syncthreads protects LDS reuse
    }

    // Final store (plain cached path).
    f32x4* xo = (f32x4*)Xout;
    #pragma unroll
    for (int r = 0; r < RPB; ++r)
        xo[(size_t)(row0 + r) * NV4 + t] = x[r];
}

extern "C" void kernel_launch(void* const* d_in, const int* in_sizes, int n_in,
                              void* d_out, int out_size, void* d_ws, size_t ws_size,
                              hipStream_t stream)
{
    const float* X0 = (const float*)d_in[0];
    float* X = (float*)d_out;

    // ws layout: colpart[256*4096] f32 (4 MB) | col_out[4096] f32 (16 KB) |
    //            flag1[256*8] u64 (16 KB) | flag2[256*8] u64 (16 KB)
    float* colpart = (float*)d_ws;
    float* col_out = colpart + (size_t)NBLK * NN;
    u64*   flag1   = (u64*)(col_out + NN);
    u64*   flag2   = flag1 + NBLK * 8;

    // Zero ONLY the flags (0xAA poison would satisfy the >= polls).
    // colpart/col_out reads are all flag-gated -> no init needed.
    hipMemsetAsync((void*)flag1, 0, 2 * NBLK * 8 * sizeof(u64), stream);

    // Regular launch: ~84 KB LDS + 16 waves -> exactly 1 block/CU,
    // grid == CU count -> all blocks co-resident (no CG API needed).
    persist8<<<dim3(NBLK), dim3(1024), 0, stream>>>(X0, X, colpart, col_out,
                                                    flag1, flag2);
}